// Round 7
// baseline (213.204 us; speedup 1.0000x reference)
//
#include <hip/hip_runtime.h>

// YOLO loss: input [B,30,7,7] f32, target [B,7,7,30] f32 -> scalar f32.
//
// Round 7: AITER-style producer-consumer DMA pipeline. Six prior kernels all
// plateau at ~72 us (2.65 TB/s demand) including L3-warm passes (FETCH~0,
// same time) -> limiter is the on-die read path OR phase serialization
// (every prior kernel alternated load/compute phases). This kernel keeps DMA
// continuously in flight: double-buffered LDS batch-pairs, exactly 6
// global_load_lds per wave per buffer, s_waitcnt vmcnt(6) (never 0!) + raw
// s_barrier (no __syncthreads -> no compiler vmcnt(0) drain), persistent
// blocks. If this also lands ~72 us, the ~2.65 TB/s read ceiling is real.

#define NCH     30
#define CELLS   49
#define TPB     256
#define NBLK    512
#define BATCH_F 1470
#define PAIR_F  2940          // floats per tensor per batch-pair (16B-aligned span)
#define CHUNKS  735           // 16B chunks per tensor per pair
#define BUF_F   (2 * PAIR_F)  // input pair + target pair
#define IMGSZ   448.0f
#define CELLSZ  64.0f

// s_waitcnt simm16 (gfx9 layout): vmcnt[3:0] | expcnt[6:4] | lgkmcnt[11:8] | vmcnt[5:4]<<14
#define W_VMCNT(n) (((n) & 15) | (0x7 << 4) | (0xF << 8) | ((((n) >> 4) & 3) << 14))
#define W_LGKM0    (0xF | (0x7 << 4) | (0x0 << 8) | (3 << 14))

__device__ __forceinline__ float iou_f(float ax1, float ay1, float ax2, float ay2,
                                       float bx1, float by1, float bx2, float by2) {
    float l  = fmaxf(ax1, bx1);
    float r  = fminf(ax2, bx2);
    float t  = fmaxf(ay1, by1);
    float bo = fminf(ay2, by2);
    bool  m  = (l < r) && (t < bo);
    float inter = (r - l) * (bo - t);
    float uni   = (ax2 - ax1) * (ay2 - ay1) + (bx2 - bx1) * (by2 - by1);
    float denom = uni - inter;
    return m ? (inter / denom) : 0.0f;
}

__device__ __forceinline__ void decode_box(float p0, float p1, float p2, float p3,
                                           float gx, float gy,
                                           float& x1, float& y1, float& x2, float& y2) {
    float cx = p0 * CELLSZ + gx;
    float cy = p1 * CELLSZ + gy;
    float w  = p2 * IMGSZ;
    float h  = p3 * IMGSZ;
    x1 = fminf(fmaxf(cx - w * 0.5f, 0.0f), IMGSZ);
    y1 = fminf(fmaxf(cy - h * 0.5f, 0.0f), IMGSZ);
    x2 = fminf(fmaxf(cx + w * 0.5f, 0.0f), IMGSZ);
    y2 = fminf(fmaxf(cy + h * 0.5f, 0.0f), IMGSZ);
}

// Issue exactly 6 DMA wave-instructions (3 per tensor) for one batch-pair.
// Chunk c -> LDS chunk c (wave-uniform base + lane*16 satisfied: c = wave*64
// + k*256 + lane). k=2 is exec-masked for lanes with c>=735 (wave 3 keeps 31
// active lanes, so the instruction still issues -> vmcnt count stays 6/wave).
__device__ __forceinline__ void issue_pair(const float* __restrict__ input,
                                           const float* __restrict__ target,
                                           float* lds_buf, long long pr, int tid) {
    const float* sin = input  + pr * PAIR_F;
    const float* stg = target + pr * PAIR_F;
    #pragma unroll
    for (int k = 0; k < 3; ++k) {
        int c = tid + k * TPB;
        if (c < CHUNKS) {
            __builtin_amdgcn_global_load_lds(
                (const __attribute__((address_space(1))) unsigned int*)(sin + c * 4),
                (__attribute__((address_space(3))) unsigned int*)(lds_buf + c * 4),
                16, 0, 0);
        }
    }
    #pragma unroll
    for (int k = 0; k < 3; ++k) {
        int c = tid + k * TPB;
        if (c < CHUNKS) {
            __builtin_amdgcn_global_load_lds(
                (const __attribute__((address_space(1))) unsigned int*)(stg + c * 4),
                (__attribute__((address_space(3))) unsigned int*)(lds_buf + PAIR_F + c * 4),
                16, 0, 0);
        }
    }
}

__global__ __launch_bounds__(TPB) void yolo_loss_kernel(
        const float* __restrict__ input,   // [B,30,7,7]
        const float* __restrict__ target,  // [B,7,7,30]
        float* __restrict__ out,
        int nbatch) {
    __shared__ __align__(16) float sbuf[2][BUF_F];   // 2 x 23520 B
    __shared__ float red[TPB / 64];

    const int tid = threadIdx.x;
    const long long npairs = (long long)nbatch >> 1;          // 8192
    const long long ppb    = (npairs + NBLK - 1) / NBLK;      // 16
    const long long p0     = (long long)blockIdx.x * ppb;

    // prologue: fill both buffers (clamped src keeps all addresses valid and
    // the per-wave DMA count uniform even for overrun blocks)
    long long c0 = p0     < npairs ? p0     : npairs - 1;
    long long c1 = p0 + 1 < npairs ? p0 + 1 : npairs - 1;
    issue_pair(input, target, sbuf[0], c0, tid);
    issue_pair(input, target, sbuf[1], c1, tid);

    float loss = 0.0f;
    for (long long j = 0; j < ppb; ++j) {
        const long long pr = p0 + j;
        float* buf = sbuf[j & 1];

        // wait for THIS buffer's 6 DMAs; the other buffer's 6 stay in flight
        __builtin_amdgcn_s_waitcnt(W_VMCNT(6));
        __builtin_amdgcn_s_barrier();
        __builtin_amdgcn_sched_barrier(0);

        if (tid < 2 * CELLS && pr < npairs) {
            const int bb  = tid / CELLS;            // batch within pair
            const int s   = tid - bb * CELLS;       // cell 0..48
            const int row = s / 7;
            const int col = s - row * 7;
            const float gx = (float)col * CELLSZ;
            const float gy = (float)row * CELLSZ;

            const float* __restrict__ ipx = buf + bb * BATCH_F + s;   // stride-49 reads
            const float* __restrict__ tl  = buf + PAIR_F + tid * NCH; // contiguous

            float x[NCH];
            #pragma unroll
            for (int c = 0; c < NCH; ++c) x[c] = ipx[c * CELLS];

            float p0x1, p0y1, p0x2, p0y2, p1x1, p1y1, p1x2, p1y2;
            decode_box(x[0], x[1], x[2], x[3], gx, gy, p0x1, p0y1, p0x2, p0y2);
            decode_box(x[5], x[6], x[7], x[8], gx, gy, p1x1, p1y1, p1x2, p1y2);
            float t0x1, t0y1, t0x2, t0y2, t1x1, t1y1, t1x2, t1y2;
            decode_box(tl[0], tl[1], tl[2], tl[3], gx, gy, t0x1, t0y1, t0x2, t0y2);
            decode_box(tl[5], tl[6], tl[7], tl[8], gx, gy, t1x1, t1y1, t1x2, t1y2);

            float iou1 = iou_f(p0x1, p0y1, p0x2, p0y2, t0x1, t0y1, t0x2, t0y2);
            float iou2 = iou_f(p1x1, p1y1, p1x2, p1y2, t1x1, t1y1, t1x2, t1y2);

            bool  mask = iou1 < iou2;
            float iou  = mask ? iou2 : iou1;
            float s0 = mask ? x[5] : x[0];
            float s1 = mask ? x[6] : x[1];
            float s2 = mask ? x[7] : x[2];
            float s3 = mask ? x[8] : x[3];
            float s4 = mask ? x[9] : x[4];

            float w = (tl[4] == 1.0f) ? 1.0f : 0.0f;

            float d0 = s0 - tl[0];
            float d1 = s1 - tl[1];
            float coord = d0 * d0 + d1 * d1;

            float ds2 = sqrtf(s2) - sqrtf(tl[2]);
            float ds3 = sqrtf(s3) - sqrtf(tl[3]);
            float size = ds2 * ds2 + ds3 * ds3;

            float dc = s4 - iou;
            float conf = dc * dc;
            float noobj = s4 * s4;

            float cls = 0.0f;
            #pragma unroll
            for (int c = 10; c < NCH; ++c) {
                float d = x[c] - tl[c];
                cls += d * d;
            }

            loss += w * (5.0f * (coord + size) + conf + cls) + 0.5f * (1.0f - w) * noobj;
        }

        // everyone done READING this buffer before refilling it
        __builtin_amdgcn_s_waitcnt(W_LGKM0);
        __builtin_amdgcn_sched_barrier(0);
        __builtin_amdgcn_s_barrier();

        long long pn = pr + 2 < npairs ? pr + 2 : npairs - 1;
        issue_pair(input, target, buf, pn, tid);
    }

    // drain leftover DMAs before reduction / endpgm
    __builtin_amdgcn_s_waitcnt(W_VMCNT(0));

    #pragma unroll
    for (int off = 32; off > 0; off >>= 1)
        loss += __shfl_down(loss, off, 64);

    const int wid  = tid >> 6;
    const int lane = tid & 63;
    if (lane == 0) red[wid] = loss;
    __syncthreads();
    if (tid == 0) {
        float s = 0.0f;
        #pragma unroll
        for (int i = 0; i < TPB / 64; ++i) s += red[i];
        atomicAdd(out, s);
    }
}

extern "C" void kernel_launch(void* const* d_in, const int* in_sizes, int n_in,
                              void* d_out, int out_size, void* d_ws, size_t ws_size,
                              hipStream_t stream) {
    const float* input  = (const float*)d_in[0];   // [B,30,7,7]
    const float* target = (const float*)d_in[1];   // [B,7,7,30]
    float* out = (float*)d_out;

    const int nbatch = in_sizes[0] / BATCH_F;      // 16384
    // d_out is poisoned 0xAA before every timed launch -> zero it (capture-safe).
    hipMemsetAsync(d_out, 0, sizeof(float), stream);
    yolo_loss_kernel<<<NBLK, TPB, 0, stream>>>(input, target, out, nbatch);
}